// Round 5
// baseline (235.962 us; speedup 1.0000x reference)
//
#include <hip/hip_runtime.h>
#include <stdint.h>

#define B_ 8
#define N_ 4096
#define C_ 512
#define H_ 256
#define NC_ 1000

typedef float v4f __attribute__((ext_vector_type(4)));
typedef short v8s __attribute__((ext_vector_type(8)));
typedef unsigned short ushort_t;

__device__ __forceinline__ uint32_t f2bf1(float f) {
    uint32_t u = __float_as_uint(f);
    return (u + 0x7FFFu + ((u >> 16) & 1u)) >> 16;
}
__device__ __forceinline__ uint32_t f2bf2(float lo, float hi) {
    return f2bf1(lo) | (f2bf1(hi) << 16);
}

// ---- prep: inverse permutation + proj_W -> bf16 B-fragment order + zero pooled
// Wfrag (uint4 units): slot[(ntile*16 + kb)*64 + q*16 + c] holds
// bf16(W[ntile*16+c][kb*32 + q*8 + j]), j=0..7.  (exact 524288 B)
__global__ void prep_kernel(const float* __restrict__ ps, const float* __restrict__ W,
                            int* __restrict__ inv, ushort_t* __restrict__ Wfrag,
                            float* __restrict__ pooled) {
    int blk = blockIdx.x, t = threadIdx.x;
    if (blk == 0) {  // zero pooled (gemm accumulates with atomics)
        float4 z = {0.f, 0.f, 0.f, 0.f};
#pragma unroll
        for (int i = 0; i < 4; i++) ((float4*)pooled)[t * 4 + i] = z;
    }
    if (blk < 128) {
        int gid = blk * 256 + t;                       // 0..32767 = b*4096 + j
        float2 p = ((const float2*)ps)[gid];
        int key = (int)(p.x + 0.5f) + 64 * (int)(p.y + 0.5f);
        int b = gid >> 12;
        inv[(b << 12) + key] = gid & 4095;             // g[b, key] = feat[b, j]
    } else {
        int i = (blk - 128) * 256 + t;                 // 0..32767 = d*64 + kb*4 + q
        int d = i >> 6, kb = (i >> 2) & 15, q = i & 3;
        const float4* src = (const float4*)(W + d * C_ + kb * 32 + q * 8);
        float4 v0 = src[0], v1 = src[1];
        uint4 pk;
        pk.x = f2bf2(v0.x, v0.y); pk.y = f2bf2(v0.z, v0.w);
        pk.z = f2bf2(v1.x, v1.y); pk.w = f2bf2(v1.z, v1.w);
        ((uint4*)Wfrag)[((d >> 4) * 16 + kb) * 64 + q * 16 + (d & 15)] = pk;
    }
}

// ---- fused gather + GEMM + bias + LN + residual column-pool -----------------
// WG: 64 rows x 512 cols, 8 waves. Phase 1 stages full K=512 A-tile (64 KB LDS,
// wave-contiguous row reads, conflict-free swizzled writes) AND streams all
// prev_out rows (so the K-loop's vmcnt queue holds only L2-hit B loads).
__global__ __launch_bounds__(512, 4)
void gemm_ln_pool(const float* __restrict__ feat, const float* __restrict__ prev,
                  const int* __restrict__ inv, const ushort_t* __restrict__ Wfrag,
                  const float* __restrict__ pb, const float* __restrict__ lg,
                  const float* __restrict__ lb, float* __restrict__ pooled) {
    __shared__ v8s Abuf[4096];          // 64 rows x 64 chunks(16B), xor-swizzled
    __shared__ float RowS[64], RowQ[64], ColS[512];

    const int t = threadIdx.x;
    const int b = blockIdx.x >> 6;
    const int row0 = (blockIdx.x & 63) << 6;
    const int wv = t >> 6, lane = t & 63, c = lane & 15, q = lane >> 4;

    if (t < 64) { RowS[t] = 0.f; RowQ[t] = 0.f; }

    // ---- phase 1a: gather inv for this wave's 8 rows ----
    const int ch = lane;                               // 16B chunk within row
    int gr[8];
#pragma unroll
    for (int s = 0; s < 8; s++)
        gr[s] = inv[(b << 12) + row0 + s * 8 + wv];

    // ---- phase 1b: stage A (one contiguous 2KB feat row per wave per step) ----
#pragma unroll 2
    for (int s = 0; s < 8; s++) {
        const float4* src = ((const float4*)(feat + ((size_t)(b * N_ + gr[s]) * C_))) + ch * 2;
        float4 f0 = src[0], f1 = src[1];
        uint4 pk;
        pk.x = f2bf2(f0.x, f0.y); pk.y = f2bf2(f0.z, f0.w);
        pk.z = f2bf2(f1.x, f1.y); pk.w = f2bf2(f1.z, f1.w);
        const int r = s * 8 + wv;                      // r&7 == wv (wave-const)
        ((uint4*)Abuf)[r * 64 + (ch ^ wv)] = pk;       // linear-permuted: no conflict
    }

    // ---- phase 1c: stream all 64 prev rows (column sums), independent loads ----
    const float* psrc = prev + ((b * N_ + row0) * C_) + t;
    float prevsum = 0.f;
#pragma unroll
    for (int g = 0; g < 8; g++) {
        float tmp[8];
#pragma unroll
        for (int r = 0; r < 8; r++) tmp[r] = psrc[(g * 8 + r) * C_];
#pragma unroll
        for (int r = 0; r < 8; r++) prevsum += tmp[r];
    }

    // B fragment bases: wave wv owns cols [64*wv, 64*wv+64), ntile = wv*4+nt
    const ushort_t* fb[4];
#pragma unroll
    for (int nt = 0; nt < 4; nt++)
        fb[nt] = Wfrag + (wv * 4 + nt) * 8192 + lane * 8;

    v4f acc[4][4];
    const v4f vzero = {0.f, 0.f, 0.f, 0.f};
#pragma unroll
    for (int mt = 0; mt < 4; mt++)
#pragma unroll
        for (int nt = 0; nt < 4; nt++) acc[mt][nt] = vzero;

    __syncthreads();

    // ---- phase 2: barrier-free K loop, only L2-hit B loads in vm queue ----
#pragma unroll 2
    for (int kb = 0; kb < 16; kb++) {
        v8s af[4], bf[4];
#pragma unroll
        for (int nt = 0; nt < 4; nt++)
            bf[nt] = *((const v8s*)(fb[nt] + kb * 512));
#pragma unroll
        for (int mt = 0; mt < 4; mt++)
            af[mt] = Abuf[(mt * 16 + c) * 64 + ((kb * 4 + q) ^ (c & 7))];
#pragma unroll
        for (int mt = 0; mt < 4; mt++)
#pragma unroll
            for (int nt = 0; nt < 4; nt++)
                acc[mt][nt] = __builtin_amdgcn_mfma_f32_16x16x32_bf16(
                    af[mt], bf[nt], acc[mt][nt], 0, 0, 0);
    }

    // ---- epilogue: bias, LN row stats, normalize, column pool ----
    float pb4[4], lg4[4], lb4[4];
#pragma unroll
    for (int nt = 0; nt < 4; nt++) {
        int n = wv * 64 + nt * 16 + c;
        pb4[nt] = pb[n]; lg4[nt] = lg[n]; lb4[nt] = lb[n];
    }
#pragma unroll
    for (int mt = 0; mt < 4; mt++) {
#pragma unroll
        for (int reg = 0; reg < 4; reg++) {
            float s1 = 0.f, s2 = 0.f;
#pragma unroll
            for (int nt = 0; nt < 4; nt++) {
                float v = acc[mt][nt][reg] + pb4[nt];
                acc[mt][nt][reg] = v;
                s1 += v; s2 += v * v;
            }
#pragma unroll
            for (int d = 1; d < 16; d <<= 1) {
                s1 += __shfl_xor(s1, d);
                s2 += __shfl_xor(s2, d);
            }
            if (c == 0) {
                int r = mt * 16 + q * 4 + reg;
                atomicAdd(&RowS[r], s1);
                atomicAdd(&RowQ[r], s2);
            }
        }
    }
    __syncthreads();
    if (t < 64) {
        float mu = RowS[t] * (1.f / C_);
        float var = RowQ[t] * (1.f / C_) - mu * mu;
        RowS[t] = mu;
        RowQ[t] = rsqrtf(var + 1e-5f);
    }
    __syncthreads();
    float col[4] = {0.f, 0.f, 0.f, 0.f};
#pragma unroll
    for (int mt = 0; mt < 4; mt++) {
#pragma unroll
        for (int reg = 0; reg < 4; reg++) {
            int r = mt * 16 + q * 4 + reg;
            float mu = RowS[r], rs = RowQ[r];
#pragma unroll
            for (int nt = 0; nt < 4; nt++)
                col[nt] += (acc[mt][nt][reg] - mu) * rs * lg4[nt] + lb4[nt];
        }
    }
#pragma unroll
    for (int nt = 0; nt < 4; nt++) {
        col[nt] += __shfl_xor(col[nt], 16);
        col[nt] += __shfl_xor(col[nt], 32);
    }
    if (lane < 16) {
#pragma unroll
        for (int nt = 0; nt < 4; nt++) ColS[wv * 64 + nt * 16 + c] = col[nt];
    }
    __syncthreads();
    atomicAdd(&pooled[b * C_ + t], ColS[t] + prevsum);
}

// ---- head: one wave per output dot product, 3 wide kernels ------------------
__global__ __launch_bounds__(256)
void head1(const float* __restrict__ pooled, const float* __restrict__ W1,
           const float* __restrict__ b1, float* __restrict__ h1) {
    const int t = threadIdx.x, wv = t >> 6, lane = t & 63;
    const int b = blockIdx.x >> 6;
    const int j = ((blockIdx.x & 63) << 2) + wv;
    const float4* wr = (const float4*)(W1 + j * C_);
    const float4* pr = (const float4*)(pooled + b * C_);
    float4 w0 = wr[lane], w1 = wr[lane + 64];
    float4 p0 = pr[lane], p1 = pr[lane + 64];
    float s = w0.x * p0.x + w0.y * p0.y + w0.z * p0.z + w0.w * p0.w
            + w1.x * p1.x + w1.y * p1.y + w1.z * p1.z + w1.w * p1.w;
#pragma unroll
    for (int d = 1; d < 64; d <<= 1) s += __shfl_xor(s, d);
    if (lane == 0) h1[b * H_ + j] = fmaxf(s * (1.f / 4096.f) + b1[j], 0.f);
}

__global__ __launch_bounds__(256)
void head2(const float* __restrict__ h1, const float* __restrict__ W2,
           const float* __restrict__ b2, float* __restrict__ h2) {
    const int t = threadIdx.x, wv = t >> 6, lane = t & 63;
    const int b = blockIdx.x >> 6;
    const int j = ((blockIdx.x & 63) << 2) + wv;
    float4 w0 = ((const float4*)(W2 + j * H_))[lane];
    float4 p0 = ((const float4*)(h1 + b * H_))[lane];
    float s = w0.x * p0.x + w0.y * p0.y + w0.z * p0.z + w0.w * p0.w;
#pragma unroll
    for (int d = 1; d < 64; d <<= 1) s += __shfl_xor(s, d);
    if (lane == 0) h2[b * H_ + j] = fmaxf(s + b2[j], 0.f);
}

__global__ __launch_bounds__(256)
void head3(const float* __restrict__ h2, const float* __restrict__ W3,
           const float* __restrict__ b3, float* __restrict__ out) {
    const int t = threadIdx.x, wv = t >> 6, lane = t & 63;
    const int b = blockIdx.x / 250;
    const int o = (blockIdx.x % 250) * 4 + wv;
    float4 w0 = ((const float4*)(W3 + o * H_))[lane];
    float4 p0 = ((const float4*)(h2 + b * H_))[lane];
    float s = w0.x * p0.x + w0.y * p0.y + w0.z * p0.z + w0.w * p0.w;
#pragma unroll
    for (int d = 1; d < 64; d <<= 1) s += __shfl_xor(s, d);
    if (lane == 0) out[b * NC_ + o] = s + b3[o];
}

extern "C" void kernel_launch(void* const* d_in, const int* in_sizes, int n_in,
                              void* d_out, int out_size, void* d_ws, size_t ws_size,
                              hipStream_t stream) {
    const float* feat  = (const float*)d_in[0];
    const float* prev  = (const float*)d_in[1];
    // d_in[2] = pos_org (implicit: key(pos_org[n]) == n) — unused
    const float* ps    = (const float*)d_in[3];
    const float* projW = (const float*)d_in[4];
    const float* pb    = (const float*)d_in[5];
    const float* lg    = (const float*)d_in[6];
    const float* lb    = (const float*)d_in[7];
    const float* W1    = (const float*)d_in[8];
    const float* b1    = (const float*)d_in[9];
    const float* W2    = (const float*)d_in[10];
    const float* b2    = (const float*)d_in[11];
    const float* W3    = (const float*)d_in[12];
    const float* b3    = (const float*)d_in[13];
    float* out = (float*)d_out;

    char* ws = (char*)d_ws;
    ushort_t* Wfrag = (ushort_t*)ws;                     // 524288 B (exact)
    int* inv        = (int*)(ws + 524288);               // 131072 B
    float* pooled   = (float*)(ws + 655360);             // 16384 B
    float* h1       = (float*)(ws + 671744);             // 8192 B
    float* h2       = (float*)(ws + 679936);             // 8192 B

    prep_kernel<<<256, 256, 0, stream>>>(ps, projW, inv, Wfrag, pooled);
    gemm_ln_pool<<<512, 512, 0, stream>>>(feat, prev, inv, Wfrag,
                                          pb, lg, lb, pooled);
    head1<<<512, 256, 0, stream>>>(pooled, W1, b1, h1);
    head2<<<512, 256, 0, stream>>>(h1, W2, b2, h2);
    head3<<<2000, 256, 0, stream>>>(h2, W3, b3, out);
}

// Round 6
// 219.334 us; speedup vs baseline: 1.0758x; 1.0758x over previous
//
#include <hip/hip_runtime.h>
#include <stdint.h>

#define B_ 8
#define N_ 4096
#define C_ 512
#define H_ 256
#define NC_ 1000

typedef float v4f __attribute__((ext_vector_type(4)));
typedef short v8s __attribute__((ext_vector_type(8)));
typedef unsigned short ushort_t;

__device__ __forceinline__ uint32_t f2bf1(float f) {
    uint32_t u = __float_as_uint(f);
    return (u + 0x7FFFu + ((u >> 16) & 1u)) >> 16;
}
__device__ __forceinline__ uint32_t pk2(float lo, float hi) {
#if __has_builtin(__builtin_amdgcn_cvt_pk_bf16_f32)
    auto r = __builtin_amdgcn_cvt_pk_bf16_f32(lo, hi);   // v_cvt_pk_bf16_f32
    return __builtin_bit_cast(uint32_t, r);
#else
    return f2bf1(lo) | (f2bf1(hi) << 16);
#endif
}

// ---- prep: inverse permutation + proj_W -> bf16 B-fragment order + zero pooled
// Wfrag (uint4 units): slot[(ntile*16 + kb)*64 + q*16 + c] holds
// bf16(W[ntile*16+c][kb*32 + q*8 + j]), j=0..7.  (exact 524288 B)
__global__ void prep_kernel(const float* __restrict__ ps, const float* __restrict__ W,
                            int* __restrict__ inv, ushort_t* __restrict__ Wfrag,
                            float* __restrict__ pooled) {
    int blk = blockIdx.x, t = threadIdx.x;
    if (blk == 0) {  // zero pooled (gemm accumulates with atomics)
        float4 z = {0.f, 0.f, 0.f, 0.f};
#pragma unroll
        for (int i = 0; i < 4; i++) ((float4*)pooled)[t * 4 + i] = z;
    }
    if (blk < 128) {
        int gid = blk * 256 + t;                       // 0..32767 = b*4096 + j
        float2 p = ((const float2*)ps)[gid];
        int key = (int)(p.x + 0.5f) + 64 * (int)(p.y + 0.5f);
        int b = gid >> 12;
        inv[(b << 12) + key] = gid & 4095;             // g[b, key] = feat[b, j]
    } else {
        int i = (blk - 128) * 256 + t;                 // 0..32767 = d*64 + kb*4 + q
        int d = i >> 6, kb = (i >> 2) & 15, q = i & 3;
        const float4* src = (const float4*)(W + d * C_ + kb * 32 + q * 8);
        float4 v0 = src[0], v1 = src[1];
        uint4 pk;
        pk.x = pk2(v0.x, v0.y); pk.y = pk2(v0.z, v0.w);
        pk.z = pk2(v1.x, v1.y); pk.w = pk2(v1.z, v1.w);
        ((uint4*)Wfrag)[((d >> 4) * 16 + kb) * 64 + q * 16 + (d & 15)] = pk;
    }
}

// ---- fused gather+GEMM+bias+LN+col-pool (512 blocks) + prev-pool (256 blocks)
// Roles interleaved in one dispatch: bid%3==2 -> prev streaming (overlaps the
// gemm blocks' MFMA phase); else gemm (round-4 structure, prev removed so the
// K-loop vm queue holds only L2-hit B loads).
__global__ __launch_bounds__(512, 4)
void gemm_ln_pool(const float* __restrict__ feat, const float* __restrict__ prev,
                  const int* __restrict__ inv, const ushort_t* __restrict__ Wfrag,
                  const float* __restrict__ pb, const float* __restrict__ lg,
                  const float* __restrict__ lb, float* __restrict__ pooled) {
    __shared__ v8s Abuf[4096];          // 64 rows x 64 chunks(16B), xor-swizzled
    __shared__ float RowS[64], RowQ[64], ColS[512];

    const int bid = blockIdx.x;
    const int t = threadIdx.x;

    if (bid % 3 == 2) {
        // ---- prev-pool role: column sums of 128 prev rows ----
        const int p = bid / 3;                          // 0..255
        const int b = p >> 5;
        const int r0 = (p & 31) << 7;                   // 128-row slab
        const float* psrc = prev + ((size_t)(b * N_ + r0) * C_) + t;
        float s0 = 0.f, s1 = 0.f, s2 = 0.f, s3 = 0.f;
#pragma unroll 4
        for (int r = 0; r < 128; r += 4) {
            s0 += psrc[(r + 0) * C_];
            s1 += psrc[(r + 1) * C_];
            s2 += psrc[(r + 2) * C_];
            s3 += psrc[(r + 3) * C_];
        }
        atomicAdd(&pooled[b * C_ + t], (s0 + s1) + (s2 + s3));
        return;
    }

    const int gix = (bid / 3) * 2 + (bid % 3);          // 0..511
    const int b = gix >> 6;
    const int row0 = (gix & 63) << 6;
    const int wv = t >> 6, lane = t & 63, c = lane & 15, q = lane >> 4;

    if (t < 64) { RowS[t] = 0.f; RowQ[t] = 0.f; }

    // ---- phase 1: stage full A tile (gather + fp32->bf16), 16 float4/thread ----
    const int arow = t >> 3;                           // 0..63
    const int acol8 = t & 7;
    const int grow = inv[(b << 12) + row0 + arow];
    const float* asrc = feat + ((size_t)(b * N_ + grow) * C_);
#pragma unroll 4
    for (int s = 0; s < 8; s++) {
        const int chunk = s * 8 + acol8;               // logical 16B-chunk 0..63
        float4 f0 = ((const float4*)asrc)[chunk * 2];
        float4 f1 = ((const float4*)asrc)[chunk * 2 + 1];
        uint4 pk;
        pk.x = pk2(f0.x, f0.y); pk.y = pk2(f0.z, f0.w);
        pk.z = pk2(f1.x, f1.y); pk.w = pk2(f1.z, f1.w);
        ((uint4*)Abuf)[arow * 64 + (chunk ^ (arow & 7))] = pk;
    }

    // B fragment bases: wave wv owns cols [64*wv, 64*wv+64), ntile = wv*4+nt
    const ushort_t* fb[4];
#pragma unroll
    for (int nt = 0; nt < 4; nt++)
        fb[nt] = Wfrag + (wv * 4 + nt) * 8192 + lane * 8;

    v4f acc[4][4];
    const v4f vzero = {0.f, 0.f, 0.f, 0.f};
#pragma unroll
    for (int mt = 0; mt < 4; mt++)
#pragma unroll
        for (int nt = 0; nt < 4; nt++) acc[mt][nt] = vzero;

    __syncthreads();

    // ---- phase 2: barrier-free K loop, only L2-hit B loads in vm queue ----
#pragma unroll 2
    for (int kb = 0; kb < 16; kb++) {
        v8s af[4], bf[4];
#pragma unroll
        for (int nt = 0; nt < 4; nt++)
            bf[nt] = *((const v8s*)(fb[nt] + kb * 512));
#pragma unroll
        for (int mt = 0; mt < 4; mt++)
            af[mt] = Abuf[(mt * 16 + c) * 64 + ((kb * 4 + q) ^ (c & 7))];
#pragma unroll
        for (int mt = 0; mt < 4; mt++)
#pragma unroll
            for (int nt = 0; nt < 4; nt++)
                acc[mt][nt] = __builtin_amdgcn_mfma_f32_16x16x32_bf16(
                    af[mt], bf[nt], acc[mt][nt], 0, 0, 0);
    }

    // ---- epilogue: bias, LN row stats, normalize, column pool ----
    float pb4[4], lg4[4], lb4[4];
#pragma unroll
    for (int nt = 0; nt < 4; nt++) {
        int n = wv * 64 + nt * 16 + c;
        pb4[nt] = pb[n]; lg4[nt] = lg[n]; lb4[nt] = lb[n];
    }
#pragma unroll
    for (int mt = 0; mt < 4; mt++) {
#pragma unroll
        for (int reg = 0; reg < 4; reg++) {
            float s1 = 0.f, s2 = 0.f;
#pragma unroll
            for (int nt = 0; nt < 4; nt++) {
                float v = acc[mt][nt][reg] + pb4[nt];
                acc[mt][nt][reg] = v;
                s1 += v; s2 += v * v;
            }
#pragma unroll
            for (int d = 1; d < 16; d <<= 1) {
                s1 += __shfl_xor(s1, d);
                s2 += __shfl_xor(s2, d);
            }
            if (c == 0) {
                int r = mt * 16 + q * 4 + reg;
                atomicAdd(&RowS[r], s1);
                atomicAdd(&RowQ[r], s2);
            }
        }
    }
    __syncthreads();
    if (t < 64) {
        float mu = RowS[t] * (1.f / C_);
        float var = RowQ[t] * (1.f / C_) - mu * mu;
        RowS[t] = mu;
        RowQ[t] = rsqrtf(var + 1e-5f);
    }
    __syncthreads();
    float col[4] = {0.f, 0.f, 0.f, 0.f};
#pragma unroll
    for (int mt = 0; mt < 4; mt++) {
#pragma unroll
        for (int reg = 0; reg < 4; reg++) {
            int r = mt * 16 + q * 4 + reg;
            float mu = RowS[r], rs = RowQ[r];
#pragma unroll
            for (int nt = 0; nt < 4; nt++)
                col[nt] += (acc[mt][nt][reg] - mu) * rs * lg4[nt] + lb4[nt];
        }
    }
#pragma unroll
    for (int nt = 0; nt < 4; nt++) {
        col[nt] += __shfl_xor(col[nt], 16);
        col[nt] += __shfl_xor(col[nt], 32);
    }
    if (lane < 16) {
#pragma unroll
        for (int nt = 0; nt < 4; nt++) ColS[wv * 64 + nt * 16 + c] = col[nt];
    }
    __syncthreads();
    atomicAdd(&pooled[b * C_ + t], ColS[t]);
}

// ---- head: single kernel. Each block: redundant h1,h2 (per-thread row dots,
// W1/W2 L2-hot) then a 40-output slice of layer 3 (wave-per-output). ----------
__global__ __launch_bounds__(256)
void head_kernel(const float* __restrict__ pooled,
                 const float* __restrict__ W1, const float* __restrict__ b1,
                 const float* __restrict__ W2, const float* __restrict__ b2,
                 const float* __restrict__ W3, const float* __restrict__ b3,
                 float* __restrict__ out) {
    __shared__ __align__(16) float P[512];
    __shared__ __align__(16) float H1[256];
    __shared__ __align__(16) float H2[256];
    const int t = threadIdx.x, wv = t >> 6, lane = t & 63;
    const int b = blockIdx.x / 25;
    const int slice = blockIdx.x % 25;                 // 25 slices x 40 outputs

    P[t] = pooled[b * C_ + t] * (1.f / 4096.f);
    P[t + 256] = pooled[b * C_ + t + 256] * (1.f / 4096.f);
    __syncthreads();

    // h1[t] = relu(W1[t,:] . P + b1[t])   (128 independent float4 loads)
    {
        const float4* wr = (const float4*)(W1 + t * C_);
        float s = 0.f;
#pragma unroll 8
        for (int k = 0; k < 128; k++) {
            float4 w = wr[k];
            float4 p = ((const float4*)P)[k];
            s += w.x * p.x + w.y * p.y + w.z * p.z + w.w * p.w;
        }
        H1[t] = fmaxf(s + b1[t], 0.f);
    }
    __syncthreads();

    // h2[t] = relu(W2[t,:] . H1 + b2[t])
    {
        const float4* wr = (const float4*)(W2 + t * H_);
        float s = 0.f;
#pragma unroll 8
        for (int k = 0; k < 64; k++) {
            float4 w = wr[k];
            float4 p = ((const float4*)H1)[k];
            s += w.x * p.x + w.y * p.y + w.z * p.z + w.w * p.w;
        }
        H2[t] = fmaxf(s + b2[t], 0.f);
    }
    __syncthreads();

    // layer 3: this block's 40 outputs, wave-per-output (coalesced W3 row)
#pragma unroll
    for (int jj = 0; jj < 10; jj++) {
        const int o = slice * 40 + jj * 4 + wv;
        float4 w = ((const float4*)(W3 + o * H_))[lane];
        float4 p = ((const float4*)H2)[lane];
        float s = w.x * p.x + w.y * p.y + w.z * p.z + w.w * p.w;
#pragma unroll
        for (int d = 1; d < 64; d <<= 1) s += __shfl_xor(s, d);
        if (lane == 0) out[b * NC_ + o] = s + b3[o];
    }
}

extern "C" void kernel_launch(void* const* d_in, const int* in_sizes, int n_in,
                              void* d_out, int out_size, void* d_ws, size_t ws_size,
                              hipStream_t stream) {
    const float* feat  = (const float*)d_in[0];
    const float* prev  = (const float*)d_in[1];
    // d_in[2] = pos_org (implicit: key(pos_org[n]) == n) — unused
    const float* ps    = (const float*)d_in[3];
    const float* projW = (const float*)d_in[4];
    const float* pb    = (const float*)d_in[5];
    const float* lg    = (const float*)d_in[6];
    const float* lb    = (const float*)d_in[7];
    const float* W1    = (const float*)d_in[8];
    const float* b1    = (const float*)d_in[9];
    const float* W2    = (const float*)d_in[10];
    const float* b2    = (const float*)d_in[11];
    const float* W3    = (const float*)d_in[12];
    const float* b3    = (const float*)d_in[13];
    float* out = (float*)d_out;

    char* ws = (char*)d_ws;
    ushort_t* Wfrag = (ushort_t*)ws;                     // 524288 B (exact)
    int* inv        = (int*)(ws + 524288);               // 131072 B
    float* pooled   = (float*)(ws + 655360);             // 16384 B

    prep_kernel<<<256, 256, 0, stream>>>(ps, projW, inv, Wfrag, pooled);
    gemm_ln_pool<<<768, 512, 0, stream>>>(feat, prev, inv, Wfrag,
                                          pb, lg, lb, pooled);
    head_kernel<<<200, 256, 0, stream>>>(pooled, W1, b1, W2, b2, W3, b3, out);
}